// Round 6
// baseline (7668.121 us; speedup 1.0000x reference)
//
#include <hip/hip_runtime.h>

#define V 256
#define H 2048
#define A 512
#define S 512
#define NBLK 64
#define NTHR 512
#define CH 64   // floats per exchange chunk slot (256B spread)

typedef float f32x4 __attribute__((ext_vector_type(4)));

// ---- coherent payload+tag chunk ops ----
__device__ __forceinline__ void st_chunk(float* p, float x, float y, int tag) {
    f32x4 v; v.x = x; v.y = y; v.z = 0.f; v.w = __int_as_float(tag);
    asm volatile("global_store_dwordx4 %0, %1, off sc0 sc1" :: "v"(p), "v"(v) : "memory");
}
__device__ __forceinline__ f32x4 ld_cg4(const float* p) {
    f32x4 r;
    asm volatile("global_load_dwordx4 %0, %1, off sc0 sc1\n\ts_waitcnt vmcnt(0)"
                 : "=&v"(r) : "v"(p) : "memory");
    return r;
}
__device__ __forceinline__ f32x4 poll1(const float* p, int tag) {
    f32x4 r = ld_cg4(p);
    while (__float_as_int(r.w) != tag) {
        __builtin_amdgcn_s_sleep(2);
        r = ld_cg4(p);
    }
    return r;
}
__device__ __forceinline__ void poll2(const float* p0, const float* p1, int tag,
                                      f32x4& a, f32x4& b) {
    a = ld_cg4(p0); b = ld_cg4(p1);
    while (__float_as_int(a.w) != tag || __float_as_int(b.w) != tag) {
        __builtin_amdgcn_s_sleep(2);
        a = ld_cg4(p0); b = ld_cg4(p1);
    }
}

__global__ void init_ex(float* p, int n) {
    int i = blockIdx.x * blockDim.x + threadIdx.x;
    if (i < n) p[i] = 0.f;
}

// ---------------- generic NT GEMM (unchanged) ----------------
__global__ __launch_bounds__(256) void gemm_nt(
    const float* __restrict__ Amat, int lda,
    const float* __restrict__ Bmat, int ldb,
    float* __restrict__ C, int ldc,
    const float* __restrict__ bias, int M, int N, int K)
{
    __shared__ float As[16][68];
    __shared__ float Bs[16][68];
    const int tid = threadIdx.x;
    const int tx = tid & 15;
    const int ty = tid >> 4;
    const int m0 = blockIdx.y * 64;
    const int n0 = blockIdx.x * 64;
    const int lr = tid >> 2;
    const int lk = (tid & 3) * 4;

    float acc[4][4] = {};
    for (int k0 = 0; k0 < K; k0 += 16) {
        float4 av = *(const float4*)(Amat + (size_t)(m0 + lr) * lda + k0 + lk);
        float4 bv = *(const float4*)(Bmat + (size_t)(n0 + lr) * ldb + k0 + lk);
        __syncthreads();
        As[lk+0][lr] = av.x; As[lk+1][lr] = av.y; As[lk+2][lr] = av.z; As[lk+3][lr] = av.w;
        Bs[lk+0][lr] = bv.x; Bs[lk+1][lr] = bv.y; Bs[lk+2][lr] = bv.z; Bs[lk+3][lr] = bv.w;
        __syncthreads();
        #pragma unroll
        for (int k = 0; k < 16; ++k) {
            float a4[4], b4[4];
            #pragma unroll
            for (int i = 0; i < 4; ++i) a4[i] = As[k][ty*4+i];
            #pragma unroll
            for (int j = 0; j < 4; ++j) b4[j] = Bs[k][tx*4+j];
            #pragma unroll
            for (int i = 0; i < 4; ++i)
                #pragma unroll
                for (int j = 0; j < 4; ++j) acc[i][j] += a4[i] * b4[j];
        }
    }
    #pragma unroll
    for (int i = 0; i < 4; ++i) {
        const int m = m0 + ty*4 + i;
        #pragma unroll
        for (int j = 0; j < 4; ++j) {
            const int n = n0 + tx*4 + j;
            float v = acc[i][j];
            if (bias) v += bias[n];
            C[(size_t)m * ldc + n] = v;
        }
    }
}

// ---------------- persistent encoder scan: 64 blocks, 4 rows/wave ----------------
__global__ __launch_bounds__(NTHR, 1) void enc_scan(
    const float* __restrict__ W_enc, const float* __restrict__ accx,
    float* __restrict__ states, float* __restrict__ hex)
{
    __shared__ __align__(16) float hs[2][H];
    const int tid = threadIdx.x;
    const int wid = tid >> 6, lane = tid & 63;
    const int w   = blockIdx.x * 8 + wid;     // 0..511, wave owns rows 4w..4w+3
    const int r0  = 4*w;

    f32x4 we[4][8];
    #pragma unroll
    for (int r = 0; r < 4; ++r)
        #pragma unroll
        for (int k = 0; k < 8; ++k)
            we[r][k] = *(const f32x4*)(W_enc + (size_t)(r0+r)*(V+H) + V + 4*(lane + 64*k));

    // t = 0
    if (lane == 0) {
        f32x4 ax = *(const f32x4*)(accx + r0);
        float h0 = tanhf(ax.x), h1 = tanhf(ax.y), h2 = tanhf(ax.z), h3 = tanhf(ax.w);
        f32x4 hv; hv.x = h0; hv.y = h1; hv.z = h2; hv.w = h3;
        *(f32x4*)(states + r0) = hv;
        st_chunk(hex + (2*w)*CH,   h0, h1, 1);
        st_chunk(hex + (2*w+1)*CH, h2, h3, 1);
    }

    for (int t = 1; t < S; ++t) {
        f32x4 ax;
        if (lane == 0) ax = *(const f32x4*)(accx + (size_t)t*H + r0);
        f32x4 ca, cb;
        const float* hb = hex + ((t-1)&1)*(1024*CH);
        poll2(hb + (2*tid)*CH, hb + (2*tid+1)*CH, t, ca, cb);
        float* dst = hs[t&1];
        dst[4*tid+0] = ca.x; dst[4*tid+1] = ca.y;
        dst[4*tid+2] = cb.x; dst[4*tid+3] = cb.y;
        __syncthreads();

        const f32x4* h4 = (const f32x4*)hs[t&1];
        float a0 = 0.f, a1 = 0.f, a2 = 0.f, a3 = 0.f;
        #pragma unroll
        for (int k = 0; k < 8; ++k) {
            f32x4 hv = h4[lane + 64*k];
            a0 += we[0][k].x*hv.x + we[0][k].y*hv.y + we[0][k].z*hv.z + we[0][k].w*hv.w;
            a1 += we[1][k].x*hv.x + we[1][k].y*hv.y + we[1][k].z*hv.z + we[1][k].w*hv.w;
            a2 += we[2][k].x*hv.x + we[2][k].y*hv.y + we[2][k].z*hv.z + we[2][k].w*hv.w;
            a3 += we[3][k].x*hv.x + we[3][k].y*hv.y + we[3][k].z*hv.z + we[3][k].w*hv.w;
        }
        #pragma unroll
        for (int off = 32; off; off >>= 1) {
            a0 += __shfl_down(a0, off); a1 += __shfl_down(a1, off);
            a2 += __shfl_down(a2, off); a3 += __shfl_down(a3, off);
        }
        if (lane == 0) {
            float h0 = tanhf(a0 + ax.x), h1 = tanhf(a1 + ax.y);
            float h2 = tanhf(a2 + ax.z), h3 = tanhf(a3 + ax.w);
            f32x4 hv; hv.x = h0; hv.y = h1; hv.z = h2; hv.w = h3;
            *(f32x4*)(states + (size_t)t*H + r0) = hv;
            float* ob = hex + (t&1)*(1024*CH);
            st_chunk(ob + (2*w)*CH,   h0, h1, t+1);
            st_chunk(ob + (2*w+1)*CH, h2, h3, t+1);
        }
    }
}

// ---------------- persistent decoder scan: 64 blocks, balanced roles ----------------
__global__ __launch_bounds__(NTHR, 1) void dec_scan(
    const float* __restrict__ Wa_dec, const float* __restrict__ W_dec,
    const float* __restrict__ enc_proj, const float* __restrict__ v_a,
    const float* __restrict__ WcT, const float* __restrict__ accx,
    const float* __restrict__ enc_states, float* __restrict__ h_dec,
    float* __restrict__ hexd, float* __restrict__ dpex, float* __restrict__ eex)
{
    __shared__ __align__(16) float hs[H];
    __shared__ __align__(16) float ps[A];
    __shared__ __align__(16) float es[S];
    __shared__ __align__(16) float va[A];
    __shared__ __align__(16) float epl[8][A];
    __shared__ float zred[8];
    const int tid = threadIdx.x;
    const int wid = tid >> 6, lane = tid & 63;
    const int w   = blockIdx.x * 8 + wid;     // 0..511; owns h-rows 4w..4w+3 AND attn row s=w
    const int r0  = 4*w;

    // register-resident weights
    f32x4 wh[4][8], wa[8], wc[4][2];
    #pragma unroll
    for (int r = 0; r < 4; ++r)
        #pragma unroll
        for (int k = 0; k < 8; ++k)
            wh[r][k] = *(const f32x4*)(W_dec + (size_t)(r0+r)*(V+2*H) + V + H + 4*(lane + 64*k));
    #pragma unroll
    for (int k = 0; k < 8; ++k)
        wa[k] = *(const f32x4*)(Wa_dec + (size_t)w*H + 4*(lane + 64*k));
    #pragma unroll
    for (int r = 0; r < 4; ++r)
        #pragma unroll
        for (int k = 0; k < 2; ++k)
            wc[r][k] = *(const f32x4*)(WcT + (size_t)(r0+r)*S + 4*(lane + 64*k));

    // LDS-resident per-wave attn data
    if (tid < A/4) ((f32x4*)va)[tid] = *(const f32x4*)(v_a + 4*tid);
    #pragma unroll
    for (int k = 0; k < 2; ++k)
        *(f32x4*)(&epl[wid][4*(lane + 64*k)]) =
            *(const f32x4*)(enc_proj + (size_t)w*A + 4*(lane + 64*k));

    const f32x4* hs4 = (const f32x4*)hs;
    const f32x4* ps4 = (const f32x4*)ps;
    const f32x4* es4 = (const f32x4*)es;

    for (int t = 0; t < S; ++t) {
        f32x4 ax;
        if (lane == 0) ax = *(const f32x4*)(accx + (size_t)t*H + r0);

        // ---- A: stage h_{t-1} ----
        if (t == 0) {
            ((f32x4*)hs)[tid] = ((const f32x4*)(enc_states + (size_t)(S-1)*H))[tid];
        } else {
            f32x4 ca, cb;
            const float* hb = hexd + ((t-1)&1)*(1024*CH);
            poll2(hb + (2*tid)*CH, hb + (2*tid+1)*CH, t, ca, cb);
            hs[4*tid+0] = ca.x; hs[4*tid+1] = ca.y;
            hs[4*tid+2] = cb.x; hs[4*tid+3] = cb.y;
        }
        __syncthreads();                                   // sync1

        // ---- B: publish dec_proj[w] ASAP, then 4-row W_h dot ----
        {
            float aP = 0.f;
            #pragma unroll
            for (int k = 0; k < 8; ++k) {
                f32x4 hv = hs4[lane + 64*k];
                aP += wa[k].x*hv.x + wa[k].y*hv.y + wa[k].z*hv.z + wa[k].w*hv.w;
            }
            #pragma unroll
            for (int off = 32; off; off >>= 1) aP += __shfl_down(aP, off);
            if (lane == 0) st_chunk(dpex + (t&1)*(512*CH) + w*CH, aP, 0.f, t+1);
        }
        float aH0 = 0.f, aH1 = 0.f, aH2 = 0.f, aH3 = 0.f;
        #pragma unroll
        for (int k = 0; k < 8; ++k) {
            f32x4 hv = hs4[lane + 64*k];
            aH0 += wh[0][k].x*hv.x + wh[0][k].y*hv.y + wh[0][k].z*hv.z + wh[0][k].w*hv.w;
            aH1 += wh[1][k].x*hv.x + wh[1][k].y*hv.y + wh[1][k].z*hv.z + wh[1][k].w*hv.w;
            aH2 += wh[2][k].x*hv.x + wh[2][k].y*hv.y + wh[2][k].z*hv.z + wh[2][k].w*hv.w;
            aH3 += wh[3][k].x*hv.x + wh[3][k].y*hv.y + wh[3][k].z*hv.z + wh[3][k].w*hv.w;
        }
        #pragma unroll
        for (int off = 32; off; off >>= 1) {
            aH0 += __shfl_down(aH0, off); aH1 += __shfl_down(aH1, off);
            aH2 += __shfl_down(aH2, off); aH3 += __shfl_down(aH3, off);
        }

        // ---- C: poll dp, compute e[w] ----
        {
            f32x4 c = poll1(dpex + (t&1)*(512*CH) + tid*CH, t+1);
            ps[tid] = c.x;
        }
        __syncthreads();                                   // sync2
        {
            float e_ = 0.f;
            #pragma unroll
            for (int k = 0; k < 2; ++k) {
                f32x4 p  = ps4[lane + 64*k];
                f32x4 e4 = *(const f32x4*)(&epl[wid][4*(lane + 64*k)]);
                f32x4 v4 = *(const f32x4*)(&va[4*(lane + 64*k)]);
                e_ += v4.x*tanhf(e4.x + p.x) + v4.y*tanhf(e4.y + p.y)
                    + v4.z*tanhf(e4.z + p.z) + v4.w*tanhf(e4.w + p.w);
            }
            #pragma unroll
            for (int off = 32; off; off >>= 1) e_ += __shfl_down(e_, off);
            if (lane == 0) st_chunk(eex + (t&1)*(512*CH) + w*CH, expf(e_), 0.f, t+1);
        }

        // ---- D: poll e ----
        {
            f32x4 c = poll1(eex + (t&1)*(512*CH) + tid*CH, t+1);
            es[tid] = c.x;
        }
        __syncthreads();                                   // syncD

        // ---- E: Z, ctx, h_new ----
        float z = es[tid];
        #pragma unroll
        for (int off = 32; off; off >>= 1) z += __shfl_down(z, off);
        if (lane == 0) zred[wid] = z;
        __syncthreads();                                   // syncZ
        const float Z = zred[0]+zred[1]+zred[2]+zred[3]+zred[4]+zred[5]+zred[6]+zred[7];

        float c0 = 0.f, c1 = 0.f, c2 = 0.f, c3 = 0.f;
        #pragma unroll
        for (int k = 0; k < 2; ++k) {
            f32x4 ev = es4[lane + 64*k];
            c0 += wc[0][k].x*ev.x + wc[0][k].y*ev.y + wc[0][k].z*ev.z + wc[0][k].w*ev.w;
            c1 += wc[1][k].x*ev.x + wc[1][k].y*ev.y + wc[1][k].z*ev.z + wc[1][k].w*ev.w;
            c2 += wc[2][k].x*ev.x + wc[2][k].y*ev.y + wc[2][k].z*ev.z + wc[2][k].w*ev.w;
            c3 += wc[3][k].x*ev.x + wc[3][k].y*ev.y + wc[3][k].z*ev.z + wc[3][k].w*ev.w;
        }
        #pragma unroll
        for (int off = 32; off; off >>= 1) {
            c0 += __shfl_down(c0, off); c1 += __shfl_down(c1, off);
            c2 += __shfl_down(c2, off); c3 += __shfl_down(c3, off);
        }
        if (lane == 0) {
            const float Zi = 1.f / Z;
            float h0 = tanhf(ax.x + aH0 + c0*Zi);
            float h1 = tanhf(ax.y + aH1 + c1*Zi);
            float h2 = tanhf(ax.z + aH2 + c2*Zi);
            float h3 = tanhf(ax.w + aH3 + c3*Zi);
            f32x4 hv; hv.x = h0; hv.y = h1; hv.z = h2; hv.w = h3;
            *(f32x4*)(h_dec + (size_t)t*H + r0) = hv;
            float* ob = hexd + (t&1)*(1024*CH);
            st_chunk(ob + (2*w)*CH,   h0, h1, t+1);
            st_chunk(ob + (2*w+1)*CH, h2, h3, t+1);
        }
    }
}

extern "C" void kernel_launch(void* const* d_in, const int* in_sizes, int n_in,
                              void* d_out, int out_size, void* d_ws, size_t ws_size,
                              hipStream_t stream) {
    const float* x_enc  = (const float*)d_in[0];
    const float* x_dec  = (const float*)d_in[1];
    const float* W_enc  = (const float*)d_in[2];
    const float* b_enc  = (const float*)d_in[3];
    const float* Wa_enc = (const float*)d_in[4];
    const float* Wa_dec = (const float*)d_in[5];
    const float* v_a    = (const float*)d_in[6];
    const float* W_dec  = (const float*)d_in[7];
    const float* b_dec  = (const float*)d_in[8];
    const float* W_out  = (const float*)d_in[9];
    const float* b_out  = (const float*)d_in[10];
    float* out = (float*)d_out;

    float* ws         = (float*)d_ws;
    float* accx_enc   = ws;                          // S*H
    float* enc_states = accx_enc + (size_t)S*H;      // S*H
    float* enc_proj   = enc_states + (size_t)S*H;    // S*A
    float* WcT        = enc_proj + (size_t)S*A;      // H*S
    float* accx_dec   = WcT + (size_t)H*S;           // S*H
    float* h_dec      = accx_dec + (size_t)S*H;      // S*H
    float* hex_e      = h_dec + (size_t)S*H;         // 2*1024*CH
    float* hex_d      = hex_e + 2*1024*CH;           // 2*1024*CH
    float* dp_ex      = hex_d + 2*1024*CH;           // 2*512*CH
    float* e_ex       = dp_ex + 2*512*CH;            // 2*512*CH
    const int n_ex = 2*1024*CH + 2*1024*CH + 2*512*CH + 2*512*CH;

    dim3 b256(256);

    init_ex<<<dim3((n_ex + 255)/256), b256, 0, stream>>>(hex_e, n_ex);

    // accx_enc = x_enc @ W_enc[:, :V].T + b_enc
    gemm_nt<<<dim3(H/64, S/64), b256, 0, stream>>>(x_enc, V, W_enc, V+H, accx_enc, H, b_enc, S, H, V);
    // accx_dec = x_dec @ W_dec[:, :V].T + b_dec
    gemm_nt<<<dim3(H/64, S/64), b256, 0, stream>>>(x_dec, V, W_dec, V+2*H, accx_dec, H, b_dec, S, H, V);

    // encoder scan
    {
        const float* We = W_enc; const float* ax = accx_enc; float* st = enc_states; float* hx = hex_e;
        void* args[] = { &We, &ax, &st, &hx };
        hipLaunchCooperativeKernel((void*)enc_scan, dim3(NBLK), dim3(NTHR), args, 0, stream);
    }

    // enc_proj = enc_states @ Wa_enc.T
    gemm_nt<<<dim3(A/64, S/64), b256, 0, stream>>>(enc_states, H, Wa_enc, H, enc_proj, A, nullptr, S, A, H);
    // WcT[i][s] = W_c[i]·enc_states[s]
    gemm_nt<<<dim3(S/64, H/64), b256, 0, stream>>>(W_dec + V, V+2*H, enc_states, H, WcT, S, nullptr, H, S, H);

    // decoder scan
    {
        const float* wa = Wa_dec; const float* wd = W_dec; const float* epj = enc_proj;
        const float* vv = v_a; const float* wc = WcT; const float* ax = accx_dec;
        const float* est = enc_states; float* hd = h_dec;
        float* hx = hex_d; float* dx = dp_ex; float* ex = e_ex;
        void* args[] = { &wa, &wd, &epj, &vv, &wc, &ax, &est, &hd, &hx, &dx, &ex };
        hipLaunchCooperativeKernel((void*)dec_scan, dim3(NBLK), dim3(NTHR), args, 0, stream);
    }

    // logits = h_dec @ W_out.T + b_out
    gemm_nt<<<dim3(V/64, S/64), b256, 0, stream>>>(h_dec, H, W_out, H, out, V, b_out, S, V, H);
}

// Round 7
// 6185.357 us; speedup vs baseline: 1.2397x; 1.2397x over previous
//
#include <hip/hip_runtime.h>

#define V 256
#define H 2048
#define A 512
#define S 512
#define NBLK 128
#define NTHR 512
#define CH 64            // floats per chunk slot (256B spread)
#define HPH (512*CH)     // h-exchange floats per phase (512 chunks)
#define DPH (128*CH)     // dp/e-exchange floats per phase (128 chunks)
#define SENTU 0x7FC00000u

typedef float f32x4 __attribute__((ext_vector_type(4)));
typedef float f32x2 __attribute__((ext_vector_type(2)));

// ---- coherent chunk ops; values self-tag (never NaN), buffers init'd to SENT ----
__device__ __forceinline__ f32x4 ld_cg4(const float* p) {
    f32x4 r;
    asm volatile("global_load_dwordx4 %0, %1, off sc0 sc1\n\ts_waitcnt vmcnt(0)"
                 : "=&v"(r) : "v"(p) : "memory");
    return r;
}
__device__ __forceinline__ f32x4 poll4(const float* p) {
    f32x4 r = ld_cg4(p);
    while (__float_as_uint(r.x) == SENTU || __float_as_uint(r.y) == SENTU ||
           __float_as_uint(r.z) == SENTU || __float_as_uint(r.w) == SENTU)
        r = ld_cg4(p);
    return r;
}
// publish: vmcnt(0) first so earlier resets/stores are at the coherence point
__device__ __forceinline__ void st_pub2(float* p, float x, float y) {
    f32x2 v; v.x = x; v.y = y;
    asm volatile("s_waitcnt vmcnt(0)\n\tglobal_store_dwordx2 %0, %1, off sc0 sc1"
                 :: "v"(p), "v"(v) : "memory");
}
__device__ __forceinline__ void st_pub1(float* p, float x) {
    asm volatile("s_waitcnt vmcnt(0)\n\tglobal_store_dword %0, %1, off sc0 sc1"
                 :: "v"(p), "v"(x) : "memory");
}
// reset (unfenced; ordered by the next publish's vmcnt)
__device__ __forceinline__ void st_rst2(float* p) {
    f32x2 v; v.x = __uint_as_float(SENTU); v.y = __uint_as_float(SENTU);
    asm volatile("global_store_dwordx2 %0, %1, off sc0 sc1" :: "v"(p), "v"(v) : "memory");
}
__device__ __forceinline__ void st_rst1(float* p) {
    float v = __uint_as_float(SENTU);
    asm volatile("global_store_dword %0, %1, off sc0 sc1" :: "v"(p), "v"(v) : "memory");
}

__global__ void init_ex(unsigned* p, int n) {
    int i = blockIdx.x * blockDim.x + threadIdx.x;
    if (i < n) p[i] = SENTU;
}

// ---------------- generic NT GEMM (unchanged) ----------------
__global__ __launch_bounds__(256) void gemm_nt(
    const float* __restrict__ Amat, int lda,
    const float* __restrict__ Bmat, int ldb,
    float* __restrict__ C, int ldc,
    const float* __restrict__ bias, int M, int N, int K)
{
    __shared__ float As[16][68];
    __shared__ float Bs[16][68];
    const int tid = threadIdx.x;
    const int tx = tid & 15;
    const int ty = tid >> 4;
    const int m0 = blockIdx.y * 64;
    const int n0 = blockIdx.x * 64;
    const int lr = tid >> 2;
    const int lk = (tid & 3) * 4;

    float acc[4][4] = {};
    for (int k0 = 0; k0 < K; k0 += 16) {
        float4 av = *(const float4*)(Amat + (size_t)(m0 + lr) * lda + k0 + lk);
        float4 bv = *(const float4*)(Bmat + (size_t)(n0 + lr) * ldb + k0 + lk);
        __syncthreads();
        As[lk+0][lr] = av.x; As[lk+1][lr] = av.y; As[lk+2][lr] = av.z; As[lk+3][lr] = av.w;
        Bs[lk+0][lr] = bv.x; Bs[lk+1][lr] = bv.y; Bs[lk+2][lr] = bv.z; Bs[lk+3][lr] = bv.w;
        __syncthreads();
        #pragma unroll
        for (int k = 0; k < 16; ++k) {
            float a4[4], b4[4];
            #pragma unroll
            for (int i = 0; i < 4; ++i) a4[i] = As[k][ty*4+i];
            #pragma unroll
            for (int j = 0; j < 4; ++j) b4[j] = Bs[k][tx*4+j];
            #pragma unroll
            for (int i = 0; i < 4; ++i)
                #pragma unroll
                for (int j = 0; j < 4; ++j) acc[i][j] += a4[i] * b4[j];
        }
    }
    #pragma unroll
    for (int i = 0; i < 4; ++i) {
        const int m = m0 + ty*4 + i;
        #pragma unroll
        for (int j = 0; j < 4; ++j) {
            const int n = n0 + tx*4 + j;
            float v = acc[i][j];
            if (bias) v += bias[n];
            C[(size_t)m * ldc + n] = v;
        }
    }
}

// ---------------- persistent encoder scan: NaN-tagged packed chunks, 3-phase ----------------
__global__ __launch_bounds__(NTHR, 2) void enc_scan(
    const float* __restrict__ W_enc, const float* __restrict__ accx,
    float* __restrict__ states, float* __restrict__ hex)
{
    __shared__ __align__(16) float hs[2][H];
    const int tid = threadIdx.x;
    const int wid = tid >> 6, lane = tid & 63;
    const int w   = blockIdx.x * 8 + wid;     // 0..1023, rows 2w,2w+1
    const int r0  = 2*w, r1 = r0 + 1;
    // this wave's 8B slot within its 16B chunk (chunk w>>1 holds rows 4(w>>1)..+3)
    const int slot = (w >> 1)*CH + (w & 1)*2;

    f32x4 we0[8], we1[8];
    #pragma unroll
    for (int k = 0; k < 8; ++k) {
        we0[k] = *(const f32x4*)(W_enc + (size_t)r0*(V+H) + V + 4*(lane + 64*k));
        we1[k] = *(const f32x4*)(W_enc + (size_t)r1*(V+H) + V + 4*(lane + 64*k));
    }

    // t = 0: h = tanh(accx) -> phase 0
    if (lane == 0) {
        float h0 = tanhf(accx[r0]), h1 = tanhf(accx[r1]);
        states[r0] = h0; states[r1] = h1;
        st_pub2(hex + slot, h0, h1);
    }

    for (int t = 1; t < S; ++t) {
        float ax0 = 0.f, ax1 = 0.f;
        if (lane == 0) { ax0 = accx[(size_t)t*H + r0]; ax1 = accx[(size_t)t*H + r1]; }

        // poll h_{t-1}: thread tid polls chunk tid (4 values)
        f32x4 c = poll4(hex + ((t-1)%3)*HPH + tid*CH);
        ((f32x4*)hs[t&1])[tid] = c;
        __syncthreads();

        // reset phase (t+1)%3 (safe: h_{t-1} observed => its readers done)
        if (lane == 0) st_rst2(hex + ((t+1)%3)*HPH + slot);

        const f32x4* h4 = (const f32x4*)hs[t&1];
        float a0 = 0.f, a1 = 0.f;
        #pragma unroll
        for (int k = 0; k < 8; ++k) {
            f32x4 hv = h4[lane + 64*k];
            a0 += we0[k].x*hv.x + we0[k].y*hv.y + we0[k].z*hv.z + we0[k].w*hv.w;
            a1 += we1[k].x*hv.x + we1[k].y*hv.y + we1[k].z*hv.z + we1[k].w*hv.w;
        }
        #pragma unroll
        for (int off = 32; off; off >>= 1) { a0 += __shfl_down(a0, off); a1 += __shfl_down(a1, off); }
        if (lane == 0) {
            float h0 = tanhf(a0 + ax0);
            float h1 = tanhf(a1 + ax1);
            states[(size_t)t*H + r0] = h0; states[(size_t)t*H + r1] = h1;
            st_pub2(hex + (t%3)*HPH + slot, h0, h1);
        }
    }
}

// ---------------- persistent decoder scan: 3 hops/step, packed chunks, even-wave attn ----------------
__global__ __launch_bounds__(NTHR, 2) void dec_scan(
    const float* __restrict__ Wa_dec, const float* __restrict__ W_dec,
    const float* __restrict__ enc_proj, const float* __restrict__ v_a,
    const float* __restrict__ WcT, const float* __restrict__ accx,
    const float* __restrict__ enc_states, float* __restrict__ h_dec,
    float* __restrict__ hexd, float* __restrict__ dpex, float* __restrict__ eex)
{
    __shared__ __align__(16) float hs[H];
    __shared__ __align__(16) float ps[A];
    __shared__ __align__(16) float es[S];
    __shared__ float zred[8];
    const int tid = threadIdx.x;
    const int wid = tid >> 6, lane = tid & 63;
    const int w   = blockIdx.x * 8 + wid;     // 0..1023, rows 2w,2w+1
    const int r0  = 2*w, r1 = r0 + 1;
    const int hslot = (w >> 1)*CH + (w & 1)*2;
    const bool attn = ((w & 1) == 0);         // even waves own attn row s = w>>1
    const int s_row = w >> 1;
    const int aslot = (s_row >> 2)*CH + (s_row & 3);   // 4B word in dp/e chunk

    f32x4 wh0[8], wh1[8], wa[8], wc0[2], wc1[2], ep[2], va[2];
    #pragma unroll
    for (int k = 0; k < 8; ++k) {
        wh0[k] = *(const f32x4*)(W_dec + (size_t)r0*(V+2*H) + V + H + 4*(lane + 64*k));
        wh1[k] = *(const f32x4*)(W_dec + (size_t)r1*(V+2*H) + V + H + 4*(lane + 64*k));
        wa[k]  = (f32x4)(0.f);
    }
    #pragma unroll
    for (int k = 0; k < 2; ++k) {
        wc0[k] = *(const f32x4*)(WcT + (size_t)r0*S + 4*(lane + 64*k));
        wc1[k] = *(const f32x4*)(WcT + (size_t)r1*S + 4*(lane + 64*k));
        ep[k] = (f32x4)(0.f); va[k] = (f32x4)(0.f);
    }
    if (attn) {
        #pragma unroll
        for (int k = 0; k < 8; ++k)
            wa[k] = *(const f32x4*)(Wa_dec + (size_t)s_row*H + 4*(lane + 64*k));
        #pragma unroll
        for (int k = 0; k < 2; ++k) {
            ep[k] = *(const f32x4*)(enc_proj + (size_t)s_row*A + 4*(lane + 64*k));
            va[k] = *(const f32x4*)(v_a + 4*(lane + 64*k));
        }
    }
    const f32x4* hs4 = (const f32x4*)hs;
    const f32x4* ps4 = (const f32x4*)ps;
    const f32x4* es4 = (const f32x4*)es;

    for (int t = 0; t < S; ++t) {
        float ax0 = 0.f, ax1 = 0.f;
        if (lane == 0) { ax0 = accx[(size_t)t*H + r0]; ax1 = accx[(size_t)t*H + r1]; }

        // ---- A: stage h_{t-1} ----
        if (t == 0) {
            ((f32x4*)hs)[tid] = ((const f32x4*)(enc_states + (size_t)(S-1)*H))[tid];
        } else {
            f32x4 c = poll4(hexd + ((t-1)%3)*HPH + tid*CH);
            ((f32x4*)hs)[tid] = c;
        }
        __syncthreads();                                   // sync1

        // resets (safe once h_{t-1} observed)
        if (t > 0 && lane == 0) {
            st_rst2(hexd + ((t+1)%3)*HPH + hslot);         // h phase read at t-1
            if (attn) {
                st_rst1(dpex + ((t-1)%3)*DPH + aslot);     // dp phase read at t-1
                st_rst1(eex  + ((t-1)%3)*DPH + aslot);     // e  phase read at t-1
            }
        }

        // ---- B: even waves publish dec_proj[s_row] ASAP, then all do W_h dots ----
        if (attn) {
            float aP = 0.f;
            #pragma unroll
            for (int k = 0; k < 8; ++k) {
                f32x4 hv = hs4[lane + 64*k];
                aP += wa[k].x*hv.x + wa[k].y*hv.y + wa[k].z*hv.z + wa[k].w*hv.w;
            }
            #pragma unroll
            for (int off = 32; off; off >>= 1) aP += __shfl_down(aP, off);
            if (lane == 0) st_pub1(dpex + (t%3)*DPH + aslot, aP);
        }
        float aH0 = 0.f, aH1 = 0.f;
        #pragma unroll
        for (int k = 0; k < 8; ++k) {
            f32x4 hv = hs4[lane + 64*k];
            aH0 += wh0[k].x*hv.x + wh0[k].y*hv.y + wh0[k].z*hv.z + wh0[k].w*hv.w;
            aH1 += wh1[k].x*hv.x + wh1[k].y*hv.y + wh1[k].z*hv.z + wh1[k].w*hv.w;
        }
        #pragma unroll
        for (int off = 32; off; off >>= 1) { aH0 += __shfl_down(aH0, off); aH1 += __shfl_down(aH1, off); }

        // ---- C: threads 0..127 poll dp (128 chunks); even waves compute e ----
        if (tid < 128) {
            f32x4 c = poll4(dpex + (t%3)*DPH + tid*CH);
            ((f32x4*)ps)[tid] = c;
        }
        __syncthreads();                                   // sync2
        if (attn) {
            float e_ = 0.f;
            #pragma unroll
            for (int k = 0; k < 2; ++k) {
                f32x4 p = ps4[lane + 64*k];
                e_ += va[k].x*tanhf(ep[k].x + p.x) + va[k].y*tanhf(ep[k].y + p.y)
                    + va[k].z*tanhf(ep[k].z + p.z) + va[k].w*tanhf(ep[k].w + p.w);
            }
            #pragma unroll
            for (int off = 32; off; off >>= 1) e_ += __shfl_down(e_, off);
            if (lane == 0) st_pub1(eex + (t%3)*DPH + aslot, expf(e_));
        }

        // ---- D: threads 0..127 poll e (128 chunks) ----
        if (tid < 128) {
            f32x4 c = poll4(eex + (t%3)*DPH + tid*CH);
            ((f32x4*)es)[tid] = c;
        }
        __syncthreads();                                   // syncD

        // ---- E: Z, ctx, h_new ----
        float z = es[tid];
        #pragma unroll
        for (int off = 32; off; off >>= 1) z += __shfl_down(z, off);
        if (lane == 0) zred[wid] = z;
        __syncthreads();                                   // syncZ
        const float Z = zred[0]+zred[1]+zred[2]+zred[3]+zred[4]+zred[5]+zred[6]+zred[7];

        float c0 = 0.f, c1 = 0.f;
        #pragma unroll
        for (int k = 0; k < 2; ++k) {
            f32x4 ev = es4[lane + 64*k];
            c0 += wc0[k].x*ev.x + wc0[k].y*ev.y + wc0[k].z*ev.z + wc0[k].w*ev.w;
            c1 += wc1[k].x*ev.x + wc1[k].y*ev.y + wc1[k].z*ev.z + wc1[k].w*ev.w;
        }
        #pragma unroll
        for (int off = 32; off; off >>= 1) { c0 += __shfl_down(c0, off); c1 += __shfl_down(c1, off); }
        if (lane == 0) {
            const float Zi = 1.f / Z;
            float h0 = tanhf(ax0 + aH0 + c0*Zi);
            float h1 = tanhf(ax1 + aH1 + c1*Zi);
            h_dec[(size_t)t*H + r0] = h0; h_dec[(size_t)t*H + r1] = h1;
            st_pub2(hexd + (t%3)*HPH + hslot, h0, h1);
        }
    }
}

extern "C" void kernel_launch(void* const* d_in, const int* in_sizes, int n_in,
                              void* d_out, int out_size, void* d_ws, size_t ws_size,
                              hipStream_t stream) {
    const float* x_enc  = (const float*)d_in[0];
    const float* x_dec  = (const float*)d_in[1];
    const float* W_enc  = (const float*)d_in[2];
    const float* b_enc  = (const float*)d_in[3];
    const float* Wa_enc = (const float*)d_in[4];
    const float* Wa_dec = (const float*)d_in[5];
    const float* v_a    = (const float*)d_in[6];
    const float* W_dec  = (const float*)d_in[7];
    const float* b_dec  = (const float*)d_in[8];
    const float* W_out  = (const float*)d_in[9];
    const float* b_out  = (const float*)d_in[10];
    float* out = (float*)d_out;

    float* ws         = (float*)d_ws;
    float* accx_enc   = ws;                          // S*H
    float* enc_states = accx_enc + (size_t)S*H;      // S*H
    float* enc_proj   = enc_states + (size_t)S*H;    // S*A
    float* WcT        = enc_proj + (size_t)S*A;      // H*S
    float* accx_dec   = WcT + (size_t)H*S;           // S*H
    float* h_dec      = accx_dec + (size_t)S*H;      // S*H
    float* hex_e      = h_dec + (size_t)S*H;         // 3*HPH
    float* hex_d      = hex_e + 3*HPH;               // 3*HPH
    float* dp_ex      = hex_d + 3*HPH;               // 3*DPH
    float* e_ex       = dp_ex + 3*DPH;               // 3*DPH
    const int n_ex = 3*HPH*2 + 3*DPH*2;

    dim3 b256(256);

    init_ex<<<dim3((n_ex + 255)/256), b256, 0, stream>>>((unsigned*)hex_e, n_ex);

    // accx_enc = x_enc @ W_enc[:, :V].T + b_enc
    gemm_nt<<<dim3(H/64, S/64), b256, 0, stream>>>(x_enc, V, W_enc, V+H, accx_enc, H, b_enc, S, H, V);
    // accx_dec = x_dec @ W_dec[:, :V].T + b_dec
    gemm_nt<<<dim3(H/64, S/64), b256, 0, stream>>>(x_dec, V, W_dec, V+2*H, accx_dec, H, b_dec, S, H, V);

    // encoder scan
    {
        const float* We = W_enc; const float* ax = accx_enc; float* st = enc_states; float* hx = hex_e;
        void* args[] = { &We, &ax, &st, &hx };
        hipLaunchCooperativeKernel((void*)enc_scan, dim3(NBLK), dim3(NTHR), args, 0, stream);
    }

    // enc_proj = enc_states @ Wa_enc.T
    gemm_nt<<<dim3(A/64, S/64), b256, 0, stream>>>(enc_states, H, Wa_enc, H, enc_proj, A, nullptr, S, A, H);
    // WcT[i][s] = W_c[i]·enc_states[s]
    gemm_nt<<<dim3(S/64, H/64), b256, 0, stream>>>(W_dec + V, V+2*H, enc_states, H, WcT, S, nullptr, H, S, H);

    // decoder scan
    {
        const float* wa = Wa_dec; const float* wd = W_dec; const float* epj = enc_proj;
        const float* vv = v_a; const float* wc = WcT; const float* ax = accx_dec;
        const float* est = enc_states; float* hd = h_dec;
        float* hx = hex_d; float* dx = dp_ex; float* ex = e_ex;
        void* args[] = { &wa, &wd, &epj, &vv, &wc, &ax, &est, &hd, &hx, &dx, &ex };
        hipLaunchCooperativeKernel((void*)dec_scan, dim3(NBLK), dim3(NTHR), args, 0, stream);
    }

    // logits = h_dec @ W_out.T + b_out
    gemm_nt<<<dim3(V/64, S/64), b256, 0, stream>>>(h_dec, H, W_out, H, out, V, b_out, S, V, H);
}

// Round 8
// 6156.003 us; speedup vs baseline: 1.2456x; 1.0048x over previous
//
#include <hip/hip_runtime.h>

#define V 256
#define H 2048
#define A 512
#define S 512
#define NBLK 128
#define NTHR 512
#define CH 64            // floats per slot (256B spread)
#define HPH (1024*CH)    // h-exchange floats per phase (1024 slots)
#define DPH (512*CH)     // dp/e-exchange floats per phase (512 slots)
#define SENTU 0x7FC00000u
#define SENT64 0x7FC000007FC00000ULL

typedef float f32x4 __attribute__((ext_vector_type(4)));
typedef unsigned long long u64;

// ---- atomic exchange primitives: RMW at the device coherence point (IC) ----
__device__ __forceinline__ void vm_drain() { asm volatile("s_waitcnt vmcnt(0)" ::: "memory"); }
__device__ __forceinline__ u64 ax_poll64(u64* p) {
    return __hip_atomic_fetch_add(p, 0ULL, __ATOMIC_RELAXED, __HIP_MEMORY_SCOPE_AGENT);
}
__device__ __forceinline__ unsigned ax_poll32(unsigned* p) {
    return __hip_atomic_fetch_add(p, 0u, __ATOMIC_RELAXED, __HIP_MEMORY_SCOPE_AGENT);
}
__device__ __forceinline__ void ax_st64(u64* p, u64 v) {
    (void)__hip_atomic_exchange(p, v, __ATOMIC_RELAXED, __HIP_MEMORY_SCOPE_AGENT);
}
__device__ __forceinline__ void ax_st32(unsigned* p, unsigned v) {
    (void)__hip_atomic_exchange(p, v, __ATOMIC_RELAXED, __HIP_MEMORY_SCOPE_AGENT);
}
__device__ __forceinline__ bool bad64(u64 v) {
    return ((unsigned)v == SENTU) || ((unsigned)(v >> 32) == SENTU);
}
__device__ __forceinline__ u64 pack2(float a, float b) {
    return ((u64)__float_as_uint(b) << 32) | (u64)__float_as_uint(a);
}

__global__ void init_ex(unsigned* p, int n) {
    int i = blockIdx.x * blockDim.x + threadIdx.x;
    if (i < n) p[i] = SENTU;
}

// ---------------- generic NT GEMM (unchanged) ----------------
__global__ __launch_bounds__(256) void gemm_nt(
    const float* __restrict__ Amat, int lda,
    const float* __restrict__ Bmat, int ldb,
    float* __restrict__ C, int ldc,
    const float* __restrict__ bias, int M, int N, int K)
{
    __shared__ float As[16][68];
    __shared__ float Bs[16][68];
    const int tid = threadIdx.x;
    const int tx = tid & 15;
    const int ty = tid >> 4;
    const int m0 = blockIdx.y * 64;
    const int n0 = blockIdx.x * 64;
    const int lr = tid >> 2;
    const int lk = (tid & 3) * 4;

    float acc[4][4] = {};
    for (int k0 = 0; k0 < K; k0 += 16) {
        float4 av = *(const float4*)(Amat + (size_t)(m0 + lr) * lda + k0 + lk);
        float4 bv = *(const float4*)(Bmat + (size_t)(n0 + lr) * ldb + k0 + lk);
        __syncthreads();
        As[lk+0][lr] = av.x; As[lk+1][lr] = av.y; As[lk+2][lr] = av.z; As[lk+3][lr] = av.w;
        Bs[lk+0][lr] = bv.x; Bs[lk+1][lr] = bv.y; Bs[lk+2][lr] = bv.z; Bs[lk+3][lr] = bv.w;
        __syncthreads();
        #pragma unroll
        for (int k = 0; k < 16; ++k) {
            float a4[4], b4[4];
            #pragma unroll
            for (int i = 0; i < 4; ++i) a4[i] = As[k][ty*4+i];
            #pragma unroll
            for (int j = 0; j < 4; ++j) b4[j] = Bs[k][tx*4+j];
            #pragma unroll
            for (int i = 0; i < 4; ++i)
                #pragma unroll
                for (int j = 0; j < 4; ++j) acc[i][j] += a4[i] * b4[j];
        }
    }
    #pragma unroll
    for (int i = 0; i < 4; ++i) {
        const int m = m0 + ty*4 + i;
        #pragma unroll
        for (int j = 0; j < 4; ++j) {
            const int n = n0 + tx*4 + j;
            float v = acc[i][j];
            if (bias) v += bias[n];
            C[(size_t)m * ldc + n] = v;
        }
    }
}

// ---------------- persistent encoder scan: atomic exchange, 3-phase ----------------
__global__ __launch_bounds__(NTHR, 2) void enc_scan(
    const float* __restrict__ W_enc, const float* __restrict__ accx,
    float* __restrict__ states, float* __restrict__ hex)
{
    __shared__ __align__(16) float hs[2][H];
    const int tid = threadIdx.x;
    const int wid = tid >> 6, lane = tid & 63;
    const int w   = blockIdx.x * 8 + wid;     // 0..1023, rows 2w,2w+1
    const int r0  = 2*w, r1 = r0 + 1;

    f32x4 we0[8], we1[8];
    #pragma unroll
    for (int k = 0; k < 8; ++k) {
        we0[k] = *(const f32x4*)(W_enc + (size_t)r0*(V+H) + V + 4*(lane + 64*k));
        we1[k] = *(const f32x4*)(W_enc + (size_t)r1*(V+H) + V + 4*(lane + 64*k));
    }

    // t = 0
    if (lane == 0) {
        float h0 = tanhf(accx[r0]), h1 = tanhf(accx[r1]);
        states[r0] = h0; states[r1] = h1;
        vm_drain();
        ax_st64((u64*)(hex + 0*HPH + w*CH), pack2(h0, h1));
    }

    for (int t = 1; t < S; ++t) {
        float ax0 = 0.f, ax1 = 0.f;
        if (lane == 0) { ax0 = accx[(size_t)t*H + r0]; ax1 = accx[(size_t)t*H + r1]; }

        // poll h_{t-1}: thread tid polls slots tid and tid+512
        {
            float* hb = hex + ((t-1)%3)*HPH;
            u64* s0 = (u64*)(hb + tid*CH);
            u64* s1 = (u64*)(hb + (tid+512)*CH);
            u64 a = ax_poll64(s0), b = ax_poll64(s1);
            while (bad64(a)) a = ax_poll64(s0);
            while (bad64(b)) b = ax_poll64(s1);
            float* dst = hs[t&1];
            dst[2*tid]        = __uint_as_float((unsigned)a);
            dst[2*tid+1]      = __uint_as_float((unsigned)(a >> 32));
            dst[1024+2*tid]   = __uint_as_float((unsigned)b);
            dst[1024+2*tid+1] = __uint_as_float((unsigned)(b >> 32));
        }
        __syncthreads();

        // reset phase (t+1)%3 (own slot; consumed globally at t-1)
        if (lane == 0) ax_st64((u64*)(hex + ((t+1)%3)*HPH + w*CH), SENT64);

        const f32x4* h4 = (const f32x4*)hs[t&1];
        float a0 = 0.f, a1 = 0.f;
        #pragma unroll
        for (int k = 0; k < 8; ++k) {
            f32x4 hv = h4[lane + 64*k];
            a0 += we0[k].x*hv.x + we0[k].y*hv.y + we0[k].z*hv.z + we0[k].w*hv.w;
            a1 += we1[k].x*hv.x + we1[k].y*hv.y + we1[k].z*hv.z + we1[k].w*hv.w;
        }
        #pragma unroll
        for (int off = 32; off; off >>= 1) { a0 += __shfl_down(a0, off); a1 += __shfl_down(a1, off); }
        if (lane == 0) {
            float h0 = tanhf(a0 + ax0);
            float h1 = tanhf(a1 + ax1);
            states[(size_t)t*H + r0] = h0; states[(size_t)t*H + r1] = h1;
            vm_drain();   // prior reset visible before this publish
            ax_st64((u64*)(hex + (t%3)*HPH + w*CH), pack2(h0, h1));
        }
    }
}

// ---------------- persistent decoder scan: atomic exchange, 3 hops/step ----------------
__global__ __launch_bounds__(NTHR, 2) void dec_scan(
    const float* __restrict__ Wa_dec, const float* __restrict__ W_dec,
    const float* __restrict__ enc_proj, const float* __restrict__ v_a,
    const float* __restrict__ WcT, const float* __restrict__ accx,
    const float* __restrict__ enc_states, float* __restrict__ h_dec,
    float* __restrict__ hexd, float* __restrict__ dpex, float* __restrict__ eex)
{
    __shared__ __align__(16) float hs[H];
    __shared__ __align__(16) float ps[A];
    __shared__ __align__(16) float es[S];
    __shared__ float zred[8];
    const int tid = threadIdx.x;
    const int wid = tid >> 6, lane = tid & 63;
    const int w   = blockIdx.x * 8 + wid;     // 0..1023, rows 2w,2w+1
    const int r0  = 2*w, r1 = r0 + 1;
    const bool attn = ((w & 1) == 0);         // even waves own attn row s = w>>1
    const int s_row = w >> 1;

    f32x4 wh0[8], wh1[8], wa[8], wc0[2], wc1[2], ep[2], va[2];
    #pragma unroll
    for (int k = 0; k < 8; ++k) {
        wh0[k] = *(const f32x4*)(W_dec + (size_t)r0*(V+2*H) + V + H + 4*(lane + 64*k));
        wh1[k] = *(const f32x4*)(W_dec + (size_t)r1*(V+2*H) + V + H + 4*(lane + 64*k));
        wa[k]  = (f32x4)(0.f);
    }
    #pragma unroll
    for (int k = 0; k < 2; ++k) {
        wc0[k] = *(const f32x4*)(WcT + (size_t)r0*S + 4*(lane + 64*k));
        wc1[k] = *(const f32x4*)(WcT + (size_t)r1*S + 4*(lane + 64*k));
        ep[k] = (f32x4)(0.f); va[k] = (f32x4)(0.f);
    }
    if (attn) {
        #pragma unroll
        for (int k = 0; k < 8; ++k)
            wa[k] = *(const f32x4*)(Wa_dec + (size_t)s_row*H + 4*(lane + 64*k));
        #pragma unroll
        for (int k = 0; k < 2; ++k) {
            ep[k] = *(const f32x4*)(enc_proj + (size_t)s_row*A + 4*(lane + 64*k));
            va[k] = *(const f32x4*)(v_a + 4*(lane + 64*k));
        }
    }
    const f32x4* hs4 = (const f32x4*)hs;
    const f32x4* ps4 = (const f32x4*)ps;
    const f32x4* es4 = (const f32x4*)es;

    for (int t = 0; t < S; ++t) {
        float ax0 = 0.f, ax1 = 0.f;
        if (lane == 0) { ax0 = accx[(size_t)t*H + r0]; ax1 = accx[(size_t)t*H + r1]; }

        // ---- A: stage h_{t-1} ----
        if (t == 0) {
            ((f32x4*)hs)[tid] = ((const f32x4*)(enc_states + (size_t)(S-1)*H))[tid];
        } else {
            float* hb = hexd + ((t-1)%3)*HPH;
            u64* s0 = (u64*)(hb + tid*CH);
            u64* s1 = (u64*)(hb + (tid+512)*CH);
            u64 a = ax_poll64(s0), b = ax_poll64(s1);
            while (bad64(a)) a = ax_poll64(s0);
            while (bad64(b)) b = ax_poll64(s1);
            hs[2*tid]        = __uint_as_float((unsigned)a);
            hs[2*tid+1]      = __uint_as_float((unsigned)(a >> 32));
            hs[1024+2*tid]   = __uint_as_float((unsigned)b);
            hs[1024+2*tid+1] = __uint_as_float((unsigned)(b >> 32));
        }
        __syncthreads();                                   // sync1

        // resets (safe once full h_{t-1} observed)
        if (t > 0 && lane == 0) {
            ax_st64((u64*)(hexd + ((t+1)%3)*HPH + w*CH), SENT64);
            if (attn) {
                ax_st32((unsigned*)(dpex + ((t-1)%3)*DPH + s_row*CH), SENTU);
                ax_st32((unsigned*)(eex  + ((t-1)%3)*DPH + s_row*CH), SENTU);
            }
        }

        // ---- B: attn waves publish dec_proj[s_row] ASAP, then all W_h dots ----
        if (attn) {
            float aP = 0.f;
            #pragma unroll
            for (int k = 0; k < 8; ++k) {
                f32x4 hv = hs4[lane + 64*k];
                aP += wa[k].x*hv.x + wa[k].y*hv.y + wa[k].z*hv.z + wa[k].w*hv.w;
            }
            #pragma unroll
            for (int off = 32; off; off >>= 1) aP += __shfl_down(aP, off);
            if (lane == 0) {
                vm_drain();
                ax_st32((unsigned*)(dpex + (t%3)*DPH + s_row*CH), __float_as_uint(aP));
            }
        }
        float aH0 = 0.f, aH1 = 0.f;
        #pragma unroll
        for (int k = 0; k < 8; ++k) {
            f32x4 hv = hs4[lane + 64*k];
            aH0 += wh0[k].x*hv.x + wh0[k].y*hv.y + wh0[k].z*hv.z + wh0[k].w*hv.w;
            aH1 += wh1[k].x*hv.x + wh1[k].y*hv.y + wh1[k].z*hv.z + wh1[k].w*hv.w;
        }
        #pragma unroll
        for (int off = 32; off; off >>= 1) { aH0 += __shfl_down(aH0, off); aH1 += __shfl_down(aH1, off); }

        // ---- C: all threads poll dp (512 slots); attn waves compute e ----
        {
            unsigned* sp = (unsigned*)(dpex + (t%3)*DPH + tid*CH);
            unsigned v = ax_poll32(sp);
            while (v == SENTU) v = ax_poll32(sp);
            ps[tid] = __uint_as_float(v);
        }
        __syncthreads();                                   // sync2
        if (attn) {
            float e_ = 0.f;
            #pragma unroll
            for (int k = 0; k < 2; ++k) {
                f32x4 p = ps4[lane + 64*k];
                e_ += va[k].x*tanhf(ep[k].x + p.x) + va[k].y*tanhf(ep[k].y + p.y)
                    + va[k].z*tanhf(ep[k].z + p.z) + va[k].w*tanhf(ep[k].w + p.w);
            }
            #pragma unroll
            for (int off = 32; off; off >>= 1) e_ += __shfl_down(e_, off);
            if (lane == 0) {
                vm_drain();
                ax_st32((unsigned*)(eex + (t%3)*DPH + s_row*CH), __float_as_uint(expf(e_)));
            }
        }

        // ---- D: all threads poll e ----
        {
            unsigned* sp = (unsigned*)(eex + (t%3)*DPH + tid*CH);
            unsigned v = ax_poll32(sp);
            while (v == SENTU) v = ax_poll32(sp);
            es[tid] = __uint_as_float(v);
        }
        __syncthreads();                                   // syncD

        // ---- E: Z, ctx, h_new ----
        float z = es[tid];
        #pragma unroll
        for (int off = 32; off; off >>= 1) z += __shfl_down(z, off);
        if (lane == 0) zred[wid] = z;
        __syncthreads();                                   // syncZ
        const float Z = zred[0]+zred[1]+zred[2]+zred[3]+zred[4]+zred[5]+zred[6]+zred[7];

        float c0 = 0.f, c1 = 0.f;
        #pragma unroll
        for (int k = 0; k < 2; ++k) {
            f32x4 ev = es4[lane + 64*k];
            c0 += wc0[k].x*ev.x + wc0[k].y*ev.y + wc0[k].z*ev.z + wc0[k].w*ev.w;
            c1 += wc1[k].x*ev.x + wc1[k].y*ev.y + wc1[k].z*ev.z + wc1[k].w*ev.w;
        }
        #pragma unroll
        for (int off = 32; off; off >>= 1) { c0 += __shfl_down(c0, off); c1 += __shfl_down(c1, off); }
        if (lane == 0) {
            const float Zi = 1.f / Z;
            float h0 = tanhf(ax0 + aH0 + c0*Zi);
            float h1 = tanhf(ax1 + aH1 + c1*Zi);
            h_dec[(size_t)t*H + r0] = h0; h_dec[(size_t)t*H + r1] = h1;
            vm_drain();   // prior resets visible before publish
            ax_st64((u64*)(hexd + (t%3)*HPH + w*CH), pack2(h0, h1));
        }
    }
}

extern "C" void kernel_launch(void* const* d_in, const int* in_sizes, int n_in,
                              void* d_out, int out_size, void* d_ws, size_t ws_size,
                              hipStream_t stream) {
    const float* x_enc  = (const float*)d_in[0];
    const float* x_dec  = (const float*)d_in[1];
    const float* W_enc  = (const float*)d_in[2];
    const float* b_enc  = (const float*)d_in[3];
    const float* Wa_enc = (const float*)d_in[4];
    const float* Wa_dec = (const float*)d_in[5];
    const float* v_a    = (const float*)d_in[6];
    const float* W_dec  = (const float*)d_in[7];
    const float* b_dec  = (const float*)d_in[8];
    const float* W_out  = (const float*)d_in[9];
    const float* b_out  = (const float*)d_in[10];
    float* out = (float*)d_out;

    float* ws         = (float*)d_ws;
    float* accx_enc   = ws;                          // S*H
    float* enc_states = accx_enc + (size_t)S*H;      // S*H
    float* enc_proj   = enc_states + (size_t)S*H;    // S*A
    float* WcT        = enc_proj + (size_t)S*A;      // H*S
    float* accx_dec   = WcT + (size_t)H*S;           // S*H
    float* h_dec      = accx_dec + (size_t)S*H;      // S*H
    float* hex_e      = h_dec + (size_t)S*H;         // 3*HPH
    float* hex_d      = hex_e + 3*HPH;               // 3*HPH
    float* dp_ex      = hex_d + 3*HPH;               // 3*DPH
    float* e_ex       = dp_ex + 3*DPH;               // 3*DPH
    const int n_ex = 3*HPH*2 + 3*DPH*2;

    dim3 b256(256);

    init_ex<<<dim3((n_ex + 255)/256), b256, 0, stream>>>((unsigned*)hex_e, n_ex);

    // accx_enc = x_enc @ W_enc[:, :V].T + b_enc
    gemm_nt<<<dim3(H/64, S/64), b256, 0, stream>>>(x_enc, V, W_enc, V+H, accx_enc, H, b_enc, S, H, V);
    // accx_dec = x_dec @ W_dec[:, :V].T + b_dec
    gemm_nt<<<dim3(H/64, S/64), b256, 0, stream>>>(x_dec, V, W_dec, V+2*H, accx_dec, H, b_dec, S, H, V);

    // encoder scan
    {
        const float* We = W_enc; const float* ax = accx_enc; float* st = enc_states; float* hx = hex_e;
        void* args[] = { &We, &ax, &st, &hx };
        hipLaunchCooperativeKernel((void*)enc_scan, dim3(NBLK), dim3(NTHR), args, 0, stream);
    }

    // enc_proj = enc_states @ Wa_enc.T
    gemm_nt<<<dim3(A/64, S/64), b256, 0, stream>>>(enc_states, H, Wa_enc, H, enc_proj, A, nullptr, S, A, H);
    // WcT[i][s] = W_c[i]·enc_states[s]
    gemm_nt<<<dim3(S/64, H/64), b256, 0, stream>>>(W_dec + V, V+2*H, enc_states, H, WcT, S, nullptr, H, S, H);

    // decoder scan
    {
        const float* wa = Wa_dec; const float* wd = W_dec; const float* epj = enc_proj;
        const float* vv = v_a; const float* wc = WcT; const float* ax = accx_dec;
        const float* est = enc_states; float* hd = h_dec;
        float* hx = hex_d; float* dx = dp_ex; float* ex = e_ex;
        void* args[] = { &wa, &wd, &epj, &vv, &wc, &ax, &est, &hd, &hx, &dx, &ex };
        hipLaunchCooperativeKernel((void*)dec_scan, dim3(NBLK), dim3(NTHR), args, 0, stream);
    }

    // logits = h_dec @ W_out.T + b_out
    gemm_nt<<<dim3(V/64, S/64), b256, 0, stream>>>(h_dec, H, W_out, H, out, V, b_out, S, V, H);
}